// Round 5
// baseline (224.410 us; speedup 1.0000x reference)
//
#include <hip/hip_runtime.h>

// DISCO S2 conv, round 5.
// prep (fat blocks): x -> xT f16 [b][h][lat][lon][32c, oct^((lon>>1)&3) swizzled],
//   weight -> wT f16 [k][f][c], taps -> metaR int4 [lat][k][tap] {psi_pk, slot*ROWB+lon*64, lon*64, 0}.
// main: 512-thr wgs (8 waves x one 16-p tile, TP=128), 69KB LDS -> 2 wg/CU = 16 waves/CU.
//   Hot loop is SMEM-free: per k, meta (96 dwords) loaded into 2 VGPRs per wave (vmcnt path),
//   per-tap scalars via compile-time v_readlane -> pure-DS lgkmcnt, fine-grained waits.
//   8 ds_read_b128 in flight per tap group, pk_fma f16 into MFMA B-frag, 4x mfma 16x16x32_f16.

#define NB    2
#define CIN   64
#define COUT  64
#define KS    9
#define NLAT  181
#define NLON  360
#define NPER  24
#define TP    128

typedef _Float16 f16;
typedef _Float16 f16x8 __attribute__((ext_vector_type(8)));
typedef float    f32x4 __attribute__((ext_vector_type(4)));
typedef unsigned int u32;
typedef unsigned short u16;
typedef u32 u32x4 __attribute__((ext_vector_type(4)));

#define ROWB       23040                                   // 360*32*2 B per slot row
#define XT_BYTES   ((size_t)NB * 2 * NLAT * NLON * 32 * 2) // 16,680,960
#define WT_BYTES   (KS * 64 * 64 * 2)                      // 73,728
#define NMETA      (KS * NLAT * NPER)                      // 39,096
#define META_BYTES ((size_t)NMETA * 16 + 256)              // +64-dword overrun pad
#define XS_BYTES   (3 * ROWB)                              // 69,120 B LDS

// ---------------- prep ------------------------------------------------------
__global__ __launch_bounds__(384) void prep_kernel(
    const float* __restrict__ x, const float* __restrict__ weight,
    const float* __restrict__ psi_vals, const int* __restrict__ psi_lat_in,
    const int* __restrict__ psi_lon_in,
    f16* __restrict__ xT, f16* __restrict__ wT, int4* __restrict__ metaR)
{
    const int tid = threadIdx.x;
    const int bx = blockIdx.x, b = blockIdx.y;
    if (bx < NLAT) {                          // x transpose: one (lat,b), all 64 c
        if (tid >= NLON) return;
        const int lat = bx, lon = tid;
        const int sw = (lon >> 1) & 3;
#pragma unroll
        for (int g = 0; g < 8; ++g) {         // 64 independent strided loads in flight
            const float* src = x + ((size_t)(b * CIN + g * 8) * NLAT + lat) * NLON + lon;
            f16x8 v;
#pragma unroll
            for (int j = 0; j < 8; ++j)
                v[j] = (f16)src[(size_t)j * NLAT * NLON];
            const int op = (g & 3) ^ sw;      // baked bank swizzle
            *(f16x8*)&xT[(((size_t)(b * 2 + (g >> 2)) * NLAT + lat) * NLON + lon) * 32
                         + op * 8] = v;
        }
        return;
    }
    if (bx == NLAT) {                         // wT[k][f][c] = W[f][c][k]
        for (int e = b * 384 + tid; e < KS * 64 * 64; e += 768) {
            int c = e & 63, f = (e >> 6) & 63, k = e >> 12;
            wT[e] = (f16)weight[((size_t)(f * 64 + c)) * KS + k];
        }
        return;
    }
    // metaR[lat][k][t] reordered packed tap metadata
    int w = ((bx - (NLAT + 1)) * 2 + b) * 384 + tid;       // 0..1535
    for (int o = w; o < NMETA; o += 1536) {
        int lat = o / 216, r = o - lat * 216;
        int k = r / 24, t = r - k * 24;
        int e = (k * NLAT + lat) * NPER + t;
        f16 pvh = (f16)psi_vals[e];
        u32 pb = (u32)__builtin_bit_cast(u16, pvh);
        int lonb = psi_lon_in[e] << 6;
        int4 m;
        m.x = (int)((pb << 16) | pb);
        m.y = (psi_lat_in[e] - lat + 1) * ROWB + lonb;     // combined byte base
        m.z = lonb;                                        // for wrap compare
        m.w = 0;
        metaR[o] = m;
    }
}

// ---------------- main ------------------------------------------------------
__global__ __launch_bounds__(512, 4) void disco_main(
    const f16* __restrict__ xT, const f16* __restrict__ wT,
    const int* __restrict__ metaI, const float* __restrict__ bias,
    float* __restrict__ out)
{
    extern __shared__ char xs[];              // [slot 3][lon 360][32c swizzled]
    const int tid  = threadIdx.x;
    const int lane = tid & 63, wave = tid >> 6;   // 8 waves
    const int pn   = lane & 15, q = lane >> 4;
    const int pchunk = blockIdx.x, lat = blockIdx.y, b = blockIdx.z;

    const int p  = pchunk * TP + wave * 16 + pn;  // 0..383 (>=360 masked at store)
    const int pl = p >= NLON ? p - NLON : p;
    const u32 plq  = (u32)((pl << 6) + (q << 4)); // p*64 + q*16
    const u32 plqm = plq - (u32)ROWB;             // wrapped variant
    const u32 thr  = (u32)((NLON - pl) << 6);     // wrap iff lon*64 >= thr

    int rr0 = lat > 0 ? lat - 1 : 0;
    int rr2 = lat < NLAT - 1 ? lat + 1 : NLAT - 1;

    f32x4 D[4];
#pragma unroll
    for (int ft = 0; ft < 4; ++ft) D[ft] = (f32x4){0.f, 0.f, 0.f, 0.f};

    const int* mi = metaI + lat * 864;            // this lat's meta, [k][t] dwords

    for (int h = 0; h < 2; ++h) {
        __syncthreads();                      // previous-half readers done
        {
            const size_t hb = (size_t)(b * 2 + h) * NLAT;
            const f16* s0 = xT + (hb + rr0) * NLON * 32;
            const f16* s1 = xT + (hb + lat) * NLON * 32;
            const f16* s2 = xT + (hb + rr2) * NLON * 32;
            for (int i = tid; i < 1440; i += 512) {
                *(f16x8*)&xs[i * 16]             = *(const f16x8*)&s0[i * 8];
                *(f16x8*)&xs[ROWB + i * 16]      = *(const f16x8*)&s1[i * 8];
                *(f16x8*)&xs[2 * ROWB + i * 16]  = *(const f16x8*)&s2[i * 8];
            }
        }
        __syncthreads();

        for (int k = 0; k < KS; ++k) {
            const int kb = k * 96;
            // this k's 24 taps (96 dwords) -> 2 VGPRs per lane, vmcnt path (no SMEM)
            const u32 vm0 = (u32)mi[kb + lane];
            const u32 vm1 = (u32)mi[kb + 64 + lane];   // pad covers last-k overrun

            f16x8 acc = (f16x8){0, 0, 0, 0, 0, 0, 0, 0};
#pragma unroll
            for (int tg = 0; tg < NPER; tg += 8) {
                u32 addr[8], pks[8];
#pragma unroll
                for (int j = 0; j < 8; ++j) {
                    const int t = tg + j, off = 4 * t;
                    u32 pk, my, mz;
                    if (off < 64) {
                        pk = (u32)__builtin_amdgcn_readlane((int)vm0, off);
                        my = (u32)__builtin_amdgcn_readlane((int)vm0, off + 1);
                        mz = (u32)__builtin_amdgcn_readlane((int)vm0, off + 2);
                    } else {
                        pk = (u32)__builtin_amdgcn_readlane((int)vm1, off - 64);
                        my = (u32)__builtin_amdgcn_readlane((int)vm1, off - 63);
                        mz = (u32)__builtin_amdgcn_readlane((int)vm1, off - 62);
                    }
                    u32 ad = (mz >= thr) ? plqm : plq;   // cmp + cndmask
                    u32 a  = my + ad;
                    addr[j] = a ^ ((a >> 3) & 48u);      // bank swizzle
                    pks[j]  = pk;
                }
                f16x8 xv[8];                             // 8 b128 in flight, pure-DS lgkm
#pragma unroll
                for (int j = 0; j < 8; ++j)
                    xv[j] = *(const f16x8*)(xs + addr[j]);
#pragma unroll
                for (int j = 0; j < 8; ++j) {
                    u32x4 pkv = {pks[j], pks[j], pks[j], pks[j]};
                    acc += xv[j] * __builtin_bit_cast(f16x8, pkv); // v_pk_fma_f16
                }
            }

            // A frags: wT[k][f][c], c = h*32 + q*8 + j, f = ft*16 + pn
            f16x8 Af[4];
            const f16* wk = wT + (size_t)k * 4096 + h * 32 + q * 8;
#pragma unroll
            for (int ft = 0; ft < 4; ++ft)
                Af[ft] = *(const f16x8*)&wk[(ft * 16 + pn) * 64];
#pragma unroll
            for (int ft = 0; ft < 4; ++ft)
                D[ft] = __builtin_amdgcn_mfma_f32_16x16x32_f16(Af[ft], acc, D[ft], 0, 0, 0);
        }
    }

    // epilogue: D[m=f][n=p], lane: col = pn, rows (lane>>4)*4 + r
    if (p < NLON) {
#pragma unroll
        for (int ft = 0; ft < 4; ++ft)
#pragma unroll
            for (int r = 0; r < 4; ++r) {
                const int f = ft * 16 + q * 4 + r;
                out[((size_t)(b * COUT + f) * NLAT + lat) * NLON + p] = D[ft][r] + bias[f];
            }
    }
}

extern "C" void kernel_launch(void* const* d_in, const int* in_sizes, int n_in,
                              void* d_out, int out_size, void* d_ws, size_t ws_size,
                              hipStream_t stream) {
    const float* x          = (const float*)d_in[0];
    const float* psi_vals   = (const float*)d_in[1];
    const float* weight     = (const float*)d_in[2];
    const float* bias       = (const float*)d_in[3];
    const int*   psi_lat_in = (const int*)d_in[6];
    const int*   psi_lon_in = (const int*)d_in[7];
    float* out = (float*)d_out;

    f16*  xT    = (f16*)d_ws;
    f16*  wT    = (f16*)((char*)d_ws + XT_BYTES);
    int4* metaR = (int4*)((char*)d_ws + XT_BYTES + WT_BYTES);

    (void)hipFuncSetAttribute((const void*)disco_main,
                              hipFuncAttributeMaxDynamicSharedMemorySize, XS_BYTES);

    prep_kernel<<<dim3(NLAT + 3, NB), 384, 0, stream>>>(
        x, weight, psi_vals, psi_lat_in, psi_lon_in, xT, wT, metaR);
    disco_main<<<dim3(3, NLAT, NB), 512, XS_BYTES, stream>>>(
        xT, wT, (const int*)metaR, bias, out);
}

// Round 6
// 191.686 us; speedup vs baseline: 1.1707x; 1.1707x over previous
//
#include <hip/hip_runtime.h>

// DISCO S2 conv, round 6.
// prep (one fat kernel, 4370x256): x -> xT f16 [b][h][lat][lon][oct^((lon>>1)&3)][8c]
//   (1 f16x8 per thread: 8 strided coalesced loads, contiguous full-line stores);
//   weight -> wT f16 [k][f][c]; taps -> meta int4 [k][lat][t] {psi_pk, slot*ROWB+lon*64, lon*64, 0}.
// main: 768-thr wgs (12 waves x one 16-p tile), 69KB LDS -> 2 wg/CU = 24 waves/CU = 6/SIMD.
//   Grid x in {0,1}: x=0 -> tiles 0..11, x=1 -> tiles 12..22 (+1 dummy wave, skips gather).
//   Per c-half: linear-stage 3 rows; per k: meta via s_load (R4 path), taps in groups of 8
//   (8 ds_read_b128 in flight), 6-VALU addressing, pk_fma f16 into B-frag, 4x mfma 16x16x32_f16.

#define NB    2
#define CIN   64
#define COUT  64
#define KS    9
#define NLAT  181
#define NLON  360
#define NPER  24

typedef _Float16 f16;
typedef _Float16 f16x8 __attribute__((ext_vector_type(8)));
typedef float    f32x4 __attribute__((ext_vector_type(4)));
typedef unsigned int u32;
typedef unsigned short u16;
typedef u32 u32x4 __attribute__((ext_vector_type(4)));

#define ROWB      23040                                   // 360*32*2 B per slot row
#define XT_BYTES  ((size_t)NB * 2 * NLAT * NLON * 32 * 2) // 16,680,960
#define WT_BYTES  (KS * 64 * 64 * 2)                      // 73,728
#define NMETA     (KS * NLAT * NPER)                      // 39,096
#define XS_BYTES  (3 * ROWB)                              // 69,120 B LDS

#define U0  (NB * 2 * 4 * NLAT * NLON)                    // 1,042,560 f16x8 units
#define G0  ((U0 + 255) / 256)                            // 4073
#define G1  ((KS * 4096 + 255) / 256)                     // 144
#define G2  ((NMETA + 255) / 256)                         // 153

// ---------------- prep ------------------------------------------------------
__global__ __launch_bounds__(256) void prep_kernel(
    const float* __restrict__ x, const float* __restrict__ weight,
    const float* __restrict__ psi_vals, const int* __restrict__ psi_lat_in,
    const int* __restrict__ psi_lon_in,
    f16* __restrict__ xT, f16* __restrict__ wT, int4* __restrict__ meta)
{
    const int bid = blockIdx.x, tid = threadIdx.x;
    if (bid < G0) {                           // x transpose, 1 f16x8 per thread
        const int u = bid * 256 + tid;
        if (u >= U0) return;
        const int oct = u & 3;
        const int v   = u >> 2;
        const int lon = v % NLON;
        const int w   = v / NLON;
        const int lat = w % NLAT;
        const int z   = w / NLAT;             // z = b*2 + h
        const int h   = z & 1, b = z >> 1;
        const float* src = x + ((size_t)(b * CIN + h * 32 + oct * 8) * NLAT + lat) * NLON + lon;
        f16x8 vv;
#pragma unroll
        for (int j = 0; j < 8; ++j)
            vv[j] = (f16)src[(size_t)j * NLAT * NLON];    // 8 independent loads
        const int op = oct ^ ((lon >> 1) & 3);            // baked bank swizzle
        *(f16x8*)&xT[(((size_t)z * NLAT + lat) * NLON + lon) * 32 + op * 8] = vv;
        return;
    }
    if (bid < G0 + G1) {                      // wT[k][f][c] = W[f][c][k]
        const int e = (bid - G0) * 256 + tid;
        if (e < KS * 4096) {
            int c = e & 63, f = (e >> 6) & 63, k = e >> 12;
            wT[e] = (f16)weight[((size_t)(f * 64 + c)) * KS + k];
        }
        return;
    }
    {                                         // packed tap metadata, [k][lat][t] order
        const int e = (bid - G0 - G1) * 256 + tid;
        if (e < NMETA) {
            int lat = (e / NPER) % NLAT;
            f16 pvh = (f16)psi_vals[e];
            u32 pb = (u32)__builtin_bit_cast(u16, pvh);
            int lonb = psi_lon_in[e] << 6;
            int4 m;
            m.x = (int)((pb << 16) | pb);
            m.y = (psi_lat_in[e] - lat + 1) * ROWB + lonb;  // combined byte base
            m.z = lonb;                                     // for wrap compare
            m.w = 0;
            meta[e] = m;
        }
    }
}

// ---------------- main ------------------------------------------------------
__global__ __launch_bounds__(768, 6) void disco_main(
    const f16* __restrict__ xT, const f16* __restrict__ wT,
    const int4* __restrict__ meta, const float* __restrict__ bias,
    float* __restrict__ out)
{
    extern __shared__ char xs[];              // [slot 3][lon 360][32c swizzled]
    const int tid  = threadIdx.x;
    const int lane = tid & 63, wave = tid >> 6;   // 12 waves
    const int pn   = lane & 15, q = lane >> 4;
    const int half2 = blockIdx.x, lat = blockIdx.y, b = blockIdx.z;

    const int tile = half2 * 12 + wave;       // 0..11 | 12..23 (23 = dummy)
    const bool act = tile < 23;               // wave-uniform
    const int p  = tile * 16 + pn;            // <= 367; >=360 masked at store
    const int pl = p >= NLON ? p - NLON : p;
    const u32 plq  = (u32)((pl << 6) + (q << 4)); // p*64 + q*16
    const u32 plqm = plq - (u32)ROWB;             // wrapped variant
    const u32 thr  = (u32)((NLON - pl) << 6);     // wrap iff lon*64 >= thr

    int rr0 = lat > 0 ? lat - 1 : 0;
    int rr2 = lat < NLAT - 1 ? lat + 1 : NLAT - 1;

    f32x4 D[4];
#pragma unroll
    for (int ft = 0; ft < 4; ++ft) D[ft] = (f32x4){0.f, 0.f, 0.f, 0.f};

    for (int h = 0; h < 2; ++h) {
        __syncthreads();                      // previous-half readers done
        {
            const size_t hb = (size_t)(b * 2 + h) * NLAT;
            const f16* s0 = xT + (hb + rr0) * NLON * 32;
            const f16* s1 = xT + (hb + lat) * NLON * 32;
            const f16* s2 = xT + (hb + rr2) * NLON * 32;
            for (int i = tid; i < 1440; i += 768) {
                *(f16x8*)&xs[i * 16]             = *(const f16x8*)&s0[i * 8];
                *(f16x8*)&xs[ROWB + i * 16]      = *(const f16x8*)&s1[i * 8];
                *(f16x8*)&xs[2 * ROWB + i * 16]  = *(const f16x8*)&s2[i * 8];
            }
        }
        __syncthreads();

        if (act) {
            for (int k = 0; k < KS; ++k) {
                f16x8 acc = (f16x8){0, 0, 0, 0, 0, 0, 0, 0};
                const int4* mp = meta + (k * NLAT + lat) * NPER;
#pragma unroll
                for (int tg = 0; tg < NPER; tg += 8) {
                    int4 m[8];
#pragma unroll
                    for (int j = 0; j < 8; ++j) m[j] = mp[tg + j];  // uniform -> s_load

                    u32 addr[8];
#pragma unroll
                    for (int j = 0; j < 8; ++j) {
                        u32 ad = ((u32)m[j].z >= thr) ? plqm : plq; // cmp + cndmask
                        u32 a  = (u32)m[j].y + ad;
                        addr[j] = a ^ ((a >> 3) & 48u);             // bank swizzle
                    }
                    f16x8 xv[8];                                    // 8 b128 in flight
#pragma unroll
                    for (int j = 0; j < 8; ++j)
                        xv[j] = *(const f16x8*)(xs + addr[j]);
#pragma unroll
                    for (int j = 0; j < 8; ++j) {
                        u32 pk = (u32)m[j].x;
                        u32x4 pkv = {pk, pk, pk, pk};
                        acc += xv[j] * __builtin_bit_cast(f16x8, pkv); // v_pk_fma_f16
                    }
                }

                // A frags: wT[k][f][c], c = h*32 + q*8 + j, f = ft*16 + pn
                f16x8 Af[4];
                const f16* wk = wT + (size_t)k * 4096 + h * 32 + q * 8;
#pragma unroll
                for (int ft = 0; ft < 4; ++ft)
                    Af[ft] = *(const f16x8*)&wk[(ft * 16 + pn) * 64];
#pragma unroll
                for (int ft = 0; ft < 4; ++ft)
                    D[ft] = __builtin_amdgcn_mfma_f32_16x16x32_f16(Af[ft], acc, D[ft], 0, 0, 0);
            }
        }
    }

    // epilogue: D[m=f][n=p], lane: col = pn, rows (lane>>4)*4 + r
    if (act && p < NLON) {
#pragma unroll
        for (int ft = 0; ft < 4; ++ft)
#pragma unroll
            for (int r = 0; r < 4; ++r) {
                const int f = ft * 16 + q * 4 + r;
                out[((size_t)(b * COUT + f) * NLAT + lat) * NLON + p] = D[ft][r] + bias[f];
            }
    }
}

extern "C" void kernel_launch(void* const* d_in, const int* in_sizes, int n_in,
                              void* d_out, int out_size, void* d_ws, size_t ws_size,
                              hipStream_t stream) {
    const float* x          = (const float*)d_in[0];
    const float* psi_vals   = (const float*)d_in[1];
    const float* weight     = (const float*)d_in[2];
    const float* bias       = (const float*)d_in[3];
    const int*   psi_lat_in = (const int*)d_in[6];
    const int*   psi_lon_in = (const int*)d_in[7];
    float* out = (float*)d_out;

    f16*  xT   = (f16*)d_ws;
    f16*  wT   = (f16*)((char*)d_ws + XT_BYTES);
    int4* meta = (int4*)((char*)d_ws + XT_BYTES + WT_BYTES);

    (void)hipFuncSetAttribute((const void*)disco_main,
                              hipFuncAttributeMaxDynamicSharedMemorySize, XS_BYTES);

    prep_kernel<<<dim3(G0 + G1 + G2), 256, 0, stream>>>(
        x, weight, psi_vals, psi_lat_in, psi_lon_in, xT, wT, meta);
    disco_main<<<dim3(2, NLAT, NB), 768, XS_BYTES, stream>>>(
        xT, wT, meta, bias, out);
}